// Round 1
// baseline (1738.243 us; speedup 1.0000x reference)
//
#include <hip/hip_runtime.h>
#include <hip/hip_bf16.h>
#include <math.h>

// Qwen3 MoE sparse block: router (top-8 of 64) + grouped SwiGLU experts.
// H=2048, I=768, E=64, K=8, T=1024. All inputs fp32; compute in bf16 MFMA
// (harness threshold 1.156e-2 = bf16-level tolerance).
//
// ws layout:
//   zbuf  : bf16[8192][768]   slot = t*8 + k          (12,582,912 B)
//   cnt   : int[64]                                    (256 B, padded)
//   elist : int[64][1024]     entry = (t<<3)|k         (262,144 B)
//   ewt   : float[64][1024]   renormalized routing wt  (262,144 B)

#define HIDDEN 2048
#define INTER  768
#define NEXP   64
#define TOPK   8
#define NTOK   1024
#define CAP    1024
#define BK     64
#define LDK    72   // padded LDS row stride (elems): 144 B = 9*16 B, 16B-aligned rows

typedef __bf16 bf16x4 __attribute__((ext_vector_type(4)));
typedef __bf16 bf16x8 __attribute__((ext_vector_type(8)));
typedef float  f32x4  __attribute__((ext_vector_type(4)));

// ---------------- Router: one wave per token, lane = expert ----------------
__global__ __launch_bounds__(64) void router_kernel(
    const float* __restrict__ x, const float* __restrict__ gw,
    int* __restrict__ cnt, int* __restrict__ elist, float* __restrict__ ewt)
{
  const int t = blockIdx.x;
  const int lane = threadIdx.x;
  const float* xr = x + (size_t)t * HIDDEN;
  const float* gr = gw + (size_t)lane * HIDDEN;

  float acc = 0.f;
  for (int h = 0; h < HIDDEN; h += 4) {
    float4 xv = *(const float4*)(xr + h);
    float4 gv = *(const float4*)(gr + h);
    acc += xv.x * gv.x + xv.y * gv.y + xv.z * gv.z + xv.w * gv.w;
  }

  // top-8 by repeated wave argmax; tie-break lower index (matches jax top_k)
  float v = acc;
  float topv[TOPK];
  int   topi[TOPK];
  #pragma unroll
  for (int k = 0; k < TOPK; ++k) {
    float mv = v; int mi = lane;
    #pragma unroll
    for (int off = 32; off > 0; off >>= 1) {
      float ov = __shfl_xor(mv, off);
      int   oi = __shfl_xor(mi, off);
      if (ov > mv || (ov == mv && oi < mi)) { mv = ov; mi = oi; }
    }
    topv[k] = mv; topi[k] = mi;
    if (lane == mi) v = -INFINITY;
  }

  // softmax over top-8 == softmax-then-renormalize of the reference
  const float m = topv[0];
  float w[TOPK], sum = 0.f;
  #pragma unroll
  for (int k = 0; k < TOPK; ++k) { w[k] = __expf(topv[k] - m); sum += w[k]; }
  const float inv = 1.f / sum;

  if (lane < TOPK) {
    const int e = topi[lane];
    const int pos = atomicAdd(&cnt[e], 1);
    elist[e * CAP + pos] = (t << 3) | lane;
    ewt[e * CAP + pos]   = w[lane] * inv;
  }
}

// ------------- Gate+Up: z = silu(x@Wg^T) * (x@Wu^T) * wt, bf16 -------------
// grid: (expert, token-tile/128, I-chunk/128), block 256 = 4 waves
__global__ __launch_bounds__(256) void gateup_kernel(
    const float* __restrict__ x, const float* __restrict__ Wg,
    const float* __restrict__ Wu, const int* __restrict__ cnt,
    const int* __restrict__ elist, const float* __restrict__ ewt,
    __bf16* __restrict__ zbuf)
{
  const int e = blockIdx.x;
  const int n_e = cnt[e];
  const int row0 = blockIdx.y * 128;
  if (row0 >= n_e) return;
  const int nrows = min(128, n_e - row0);
  const int nchunk = blockIdx.z;

  __shared__ __bf16 As[128 * LDK];
  __shared__ __bf16 Gs[128 * LDK];
  __shared__ __bf16 Us[128 * LDK];
  __shared__ int   s_slot[128];
  __shared__ float s_wt[128];

  const int tid = threadIdx.x;
  if (tid < 128) {
    if (tid < nrows) {
      s_slot[tid] = elist[e * CAP + row0 + tid];
      s_wt[tid]   = ewt[e * CAP + row0 + tid];
    } else { s_slot[tid] = -1; s_wt[tid] = 0.f; }
  }

  const int wave = tid >> 6, lane = tid & 63;
  const int wm = wave >> 1, wn = wave & 1;
  const int lq = lane >> 4, lr = lane & 15;
  const int lrow = tid >> 4;        // staging row 0..15
  const int lc   = (tid & 15) * 4;  // staging col (elems), float4 granularity

  const float* Wgb = Wg + ((size_t)e * INTER + (size_t)nchunk * 128) * HIDDEN;
  const float* Wub = Wu + ((size_t)e * INTER + (size_t)nchunk * 128) * HIDDEN;

  f32x4 accg[16], accu[16];
  #pragma unroll
  for (int i = 0; i < 16; ++i) {
    accg[i] = (f32x4){0.f, 0.f, 0.f, 0.f};
    accu[i] = (f32x4){0.f, 0.f, 0.f, 0.f};
  }

  __syncthreads();  // s_slot/s_wt visible

  for (int k0 = 0; k0 < HIDDEN; k0 += BK) {
    #pragma unroll
    for (int i = 0; i < 8; ++i) {
      const int r = lrow + i * 16;
      const int s = s_slot[r];
      float4 xv = make_float4(0.f, 0.f, 0.f, 0.f);
      if (s >= 0) xv = *(const float4*)(x + (size_t)(s >> 3) * HIDDEN + k0 + lc);
      bf16x4 xb = { (__bf16)xv.x, (__bf16)xv.y, (__bf16)xv.z, (__bf16)xv.w };
      *(bf16x4*)(As + r * LDK + lc) = xb;
      float4 gv = *(const float4*)(Wgb + (size_t)r * HIDDEN + k0 + lc);
      bf16x4 gb = { (__bf16)gv.x, (__bf16)gv.y, (__bf16)gv.z, (__bf16)gv.w };
      *(bf16x4*)(Gs + r * LDK + lc) = gb;
      float4 uv = *(const float4*)(Wub + (size_t)r * HIDDEN + k0 + lc);
      bf16x4 ub = { (__bf16)uv.x, (__bf16)uv.y, (__bf16)uv.z, (__bf16)uv.w };
      *(bf16x4*)(Us + r * LDK + lc) = ub;
    }
    __syncthreads();
    #pragma unroll
    for (int ks = 0; ks < BK; ks += 32) {
      bf16x8 a[4], bg[4], bu[4];
      #pragma unroll
      for (int mi = 0; mi < 4; ++mi)
        a[mi] = *(const bf16x8*)(As + (wm * 64 + mi * 16 + lr) * LDK + ks + lq * 8);
      #pragma unroll
      for (int ni = 0; ni < 4; ++ni) {
        bg[ni] = *(const bf16x8*)(Gs + (wn * 64 + ni * 16 + lr) * LDK + ks + lq * 8);
        bu[ni] = *(const bf16x8*)(Us + (wn * 64 + ni * 16 + lr) * LDK + ks + lq * 8);
      }
      #pragma unroll
      for (int mi = 0; mi < 4; ++mi)
        #pragma unroll
        for (int ni = 0; ni < 4; ++ni) {
          accg[mi * 4 + ni] = __builtin_amdgcn_mfma_f32_16x16x32_bf16(
              a[mi], bg[ni], accg[mi * 4 + ni], 0, 0, 0);
          accu[mi * 4 + ni] = __builtin_amdgcn_mfma_f32_16x16x32_bf16(
              a[mi], bu[ni], accu[mi * 4 + ni], 0, 0, 0);
        }
    }
    __syncthreads();
  }

  // epilogue: z = silu(g)*u*wt -> bf16 slot store
  #pragma unroll
  for (int mi = 0; mi < 4; ++mi) {
    #pragma unroll
    for (int ni = 0; ni < 4; ++ni) {
      f32x4 g = accg[mi * 4 + ni], u = accu[mi * 4 + ni];
      const int colg = nchunk * 128 + wn * 64 + ni * 16 + lr;
      #pragma unroll
      for (int j = 0; j < 4; ++j) {
        const int r = wm * 64 + mi * 16 + lq * 4 + j;
        if (r < nrows) {
          const float gg = g[j];
          const float z = gg / (1.f + __expf(-gg)) * u[j] * s_wt[r];
          zbuf[(size_t)s_slot[r] * INTER + colg] = (__bf16)z;
        }
      }
    }
  }
}

// ---------------- Down: out[t,h] += z @ Wd^T (atomic scatter) ---------------
// grid: (expert, token-tile/128, H-chunk/128), block 256 = 4 waves
__global__ __launch_bounds__(256) void down_kernel(
    const __bf16* __restrict__ zbuf, const float* __restrict__ Wd,
    const int* __restrict__ cnt, const int* __restrict__ elist,
    float* __restrict__ out)
{
  const int e = blockIdx.x;
  const int n_e = cnt[e];
  const int row0 = blockIdx.y * 128;
  if (row0 >= n_e) return;
  const int nrows = min(128, n_e - row0);
  const int hc = blockIdx.z;

  __shared__ __bf16 As[128 * LDK];
  __shared__ __bf16 Bs[128 * LDK];
  __shared__ int s_slot[128];

  const int tid = threadIdx.x;
  if (tid < 128) s_slot[tid] = (tid < nrows) ? elist[e * CAP + row0 + tid] : -1;

  const int wave = tid >> 6, lane = tid & 63;
  const int wm = wave >> 1, wn = wave & 1;
  const int lq = lane >> 4, lr = lane & 15;
  const int lrow = tid >> 4;
  const int lc   = (tid & 15) * 4;

  const float* Wb = Wd + ((size_t)e * HIDDEN + (size_t)hc * 128) * INTER;

  f32x4 acc[16];
  #pragma unroll
  for (int i = 0; i < 16; ++i) acc[i] = (f32x4){0.f, 0.f, 0.f, 0.f};

  __syncthreads();

  for (int k0 = 0; k0 < INTER; k0 += BK) {
    #pragma unroll
    for (int i = 0; i < 8; ++i) {
      const int r = lrow + i * 16;
      const int s = s_slot[r];
      bf16x4 av = { (__bf16)0.f, (__bf16)0.f, (__bf16)0.f, (__bf16)0.f };
      if (s >= 0) av = *(const bf16x4*)(zbuf + (size_t)s * INTER + k0 + lc);
      *(bf16x4*)(As + r * LDK + lc) = av;
      float4 wv = *(const float4*)(Wb + (size_t)r * INTER + k0 + lc);
      bf16x4 wb = { (__bf16)wv.x, (__bf16)wv.y, (__bf16)wv.z, (__bf16)wv.w };
      *(bf16x4*)(Bs + r * LDK + lc) = wb;
    }
    __syncthreads();
    #pragma unroll
    for (int ks = 0; ks < BK; ks += 32) {
      bf16x8 a[4], b[4];
      #pragma unroll
      for (int mi = 0; mi < 4; ++mi)
        a[mi] = *(const bf16x8*)(As + (wm * 64 + mi * 16 + lr) * LDK + ks + lq * 8);
      #pragma unroll
      for (int ni = 0; ni < 4; ++ni)
        b[ni] = *(const bf16x8*)(Bs + (wn * 64 + ni * 16 + lr) * LDK + ks + lq * 8);
      #pragma unroll
      for (int mi = 0; mi < 4; ++mi)
        #pragma unroll
        for (int ni = 0; ni < 4; ++ni)
          acc[mi * 4 + ni] = __builtin_amdgcn_mfma_f32_16x16x32_bf16(
              a[mi], b[ni], acc[mi * 4 + ni], 0, 0, 0);
    }
    __syncthreads();
  }

  #pragma unroll
  for (int mi = 0; mi < 4; ++mi) {
    #pragma unroll
    for (int ni = 0; ni < 4; ++ni) {
      const int h = hc * 128 + wn * 64 + ni * 16 + lr;
      #pragma unroll
      for (int j = 0; j < 4; ++j) {
        const int r = wm * 64 + mi * 16 + lq * 4 + j;
        if (r < nrows) {
          const int t = s_slot[r] >> 3;
          atomicAdd(out + (size_t)t * HIDDEN + h, acc[mi * 4 + ni][j]);
        }
      }
    }
  }
}

extern "C" void kernel_launch(void* const* d_in, const int* in_sizes, int n_in,
                              void* d_out, int out_size, void* d_ws, size_t ws_size,
                              hipStream_t stream) {
  const float* x  = (const float*)d_in[0];
  const float* gw = (const float*)d_in[1];
  const float* Wg = (const float*)d_in[2];
  const float* Wu = (const float*)d_in[3];
  const float* Wd = (const float*)d_in[4];
  float* out = (float*)d_out;

  char* ws = (char*)d_ws;
  __bf16* zbuf = (__bf16*)ws;                                   // 12,582,912 B
  int*    cnt  = (int*)(ws + 12582912);                         // 256 B
  int*    elist= (int*)(ws + 12582912 + 256);                   // 262,144 B
  float*  ewt  = (float*)(ws + 12582912 + 256 + 262144);        // 262,144 B

  hipMemsetAsync(cnt, 0, NEXP * sizeof(int), stream);
  hipMemsetAsync(out, 0, (size_t)out_size * sizeof(float), stream);

  router_kernel<<<NTOK, 64, 0, stream>>>(x, gw, cnt, elist, ewt);
  gateup_kernel<<<dim3(NEXP, 8, 6), 256, 0, stream>>>(x, Wg, Wu, cnt, elist, ewt, zbuf);
  down_kernel<<<dim3(NEXP, 8, 16), 256, 0, stream>>>(zbuf, Wd, cnt, elist, out);
}